// Round 2
// baseline (394.584 us; speedup 1.0000x reference)
//
#include <hip/hip_runtime.h>
#include <hip/hip_bf16.h>
#include <stdint.h>

// Problem constants: b=2, s=2048, d=1024, H=16, DH=64, inner=1024
// All external tensors are FP32 (reference dtypes). Internal compute is bf16 MFMA.
#define NH     16
#define DHEAD  64
#define SEQ    2048
#define DMODEL 1024
#define NBATCH 2
#define INNER  1024
#define QKVN   3072
#define ROWS   4096      // NBATCH*SEQ
#define ATT_SCALE 0.125f // DHEAD^-0.5

typedef __attribute__((ext_vector_type(8))) __bf16 bf16x8;
typedef __attribute__((ext_vector_type(4))) float floatx4;

__device__ __forceinline__ float bf2f(unsigned short u) {
    union { unsigned int i; float f; } c; c.i = ((unsigned int)u) << 16; return c.f;
}
__device__ __forceinline__ unsigned short f2bf(float f) {
    union { __bf16 b; unsigned short u; } c; c.b = (__bf16)f; return c.u;
}
__device__ __forceinline__ void storeC(float* p, float v) { *p = v; }
__device__ __forceinline__ void storeC(unsigned short* p, float v) { *p = f2bf(v); }

// ------- transpose + fp32->bf16: out[c][r] = bf16(in[r][c]) ---------------------
__global__ __launch_bounds__(256) void transpose_f2b(
        const float* __restrict__ in, unsigned short* __restrict__ out,
        int rows, int cols) {
    __shared__ unsigned short tile[32][33];
    const int bx = blockIdx.x * 32, by = blockIdx.y * 32;
    const int tx = threadIdx.x & 31, ty = threadIdx.x >> 5;   // ty: 0..7
    for (int i = ty; i < 32; i += 8)
        tile[i][tx] = f2bf(in[(size_t)(by + i) * cols + bx + tx]);
    __syncthreads();
    for (int i = ty; i < 32; i += 8)
        out[(size_t)(bx + i) * rows + by + tx] = tile[tx][i];
}

// ------- layernorm fp32 in -> bf16 out: one block per row (1024, 256 thr x 4) --
__global__ __launch_bounds__(256) void ln_kernel(
        const float* __restrict__ x,
        const float* __restrict__ gamma,
        const float* __restrict__ beta,
        unsigned short* __restrict__ xn) {
    __shared__ float red[4][2];
    const int row = blockIdx.x, t = threadIdx.x;
    const size_t base = (size_t)row * DMODEL + t * 4;
    float4 v = *(const float4*)(x + base);
    float s  = v.x + v.y + v.z + v.w;
    float ss = v.x*v.x + v.y*v.y + v.z*v.z + v.w*v.w;
    for (int off = 32; off >= 1; off >>= 1) {
        s  += __shfl_xor(s,  off);
        ss += __shfl_xor(ss, off);
    }
    const int w = t >> 6, lane = t & 63;
    if (lane == 0) { red[w][0] = s; red[w][1] = ss; }
    __syncthreads();
    if (t == 0) {
        float S  = red[0][0] + red[1][0] + red[2][0] + red[3][0];
        float SS = red[0][1] + red[1][1] + red[2][1] + red[3][1];
        float mu  = S * (1.f / DMODEL);
        float var = SS * (1.f / DMODEL) - mu * mu;
        red[0][0] = mu; red[0][1] = rsqrtf(var + 1e-5f);
    }
    __syncthreads();
    const float mu = red[0][0], rstd = red[0][1];
    float4 g = *(const float4*)(gamma + t * 4);
    float4 bb = *(const float4*)(beta + t * 4);
    ushort4 o;
    o.x = f2bf((v.x - mu) * rstd * g.x + bb.x);
    o.y = f2bf((v.y - mu) * rstd * g.y + bb.y);
    o.z = f2bf((v.z - mu) * rstd * g.z + bb.z);
    o.w = f2bf((v.w - mu) * rstd * g.w + bb.w);
    *(ushort4*)(xn + base) = o;
}

// ------- C[M,N] = A[M,K] * Bt[N,K]^T (+fp32 bias), 128x128 tile, BK=32 ---------
// 256 thr = 4 waves in 2x2; each wave 64x64 via 4x4 grid of 16x16x32 MFMA.
// OUT = unsigned short (bf16) or float.
template <typename OUT>
__global__ __launch_bounds__(256) void gemm_bt(
        const unsigned short* __restrict__ A,
        const unsigned short* __restrict__ Bt,
        OUT* __restrict__ C,
        const int M, const int N, const int K,
        const float* __restrict__ bias) {
    __shared__ __align__(16) unsigned short sA[128 * 32];
    __shared__ __align__(16) unsigned short sB[128 * 32];
    const int t = threadIdx.x;
    const int mBase = blockIdx.y * 128, nBase = blockIdx.x * 128;
    const int w = t >> 6, lane = t & 63, quad = lane >> 4, l16 = lane & 15;
    const int wm = (w >> 1) * 64, wn = (w & 1) * 64;
    floatx4 acc[4][4];
    for (int mi = 0; mi < 4; mi++)
        for (int ni = 0; ni < 4; ni++) acc[mi][ni] = (floatx4)0.f;

    for (int k0 = 0; k0 < K; k0 += 32) {
        #pragma unroll
        for (int c = 0; c < 2; c++) {
            const int idx = c * 256 + t;
            const int row = idx >> 2, colE = (idx & 3) * 8;
            *(uint4*)&sA[row * 32 + colE] =
                *(const uint4*)&A[(size_t)(mBase + row) * K + k0 + colE];
            *(uint4*)&sB[row * 32 + colE] =
                *(const uint4*)&Bt[(size_t)(nBase + row) * K + k0 + colE];
        }
        __syncthreads();
        bf16x8 af[4], bfv[4];
        #pragma unroll
        for (int mi = 0; mi < 4; mi++)
            af[mi] = *(const bf16x8*)&sA[(wm + mi * 16 + l16) * 32 + quad * 8];
        #pragma unroll
        for (int ni = 0; ni < 4; ni++)
            bfv[ni] = *(const bf16x8*)&sB[(wn + ni * 16 + l16) * 32 + quad * 8];
        #pragma unroll
        for (int mi = 0; mi < 4; mi++)
            #pragma unroll
            for (int ni = 0; ni < 4; ni++)
                acc[mi][ni] = __builtin_amdgcn_mfma_f32_16x16x32_bf16(
                    af[mi], bfv[ni], acc[mi][ni], 0, 0, 0);
        __syncthreads();
    }
    #pragma unroll
    for (int mi = 0; mi < 4; mi++)
        #pragma unroll
        for (int ni = 0; ni < 4; ni++) {
            const int col = nBase + wn + ni * 16 + l16;
            const float badd = bias ? bias[col] : 0.f;
            #pragma unroll
            for (int i = 0; i < 4; i++) {
                const int row = mBase + wm + mi * 16 + quad * 4 + i;
                storeC(&C[(size_t)row * N + col], acc[mi][ni][i] + badd);
            }
        }
}

// ------- flash attention: 64 q rows / block (16 per wave), KV tile = 32 --------
// qkv: [ROWS, 3072] bf16 (q | k | v, head h at cols h*64). aout: [ROWS, 1024] bf16.
__global__ __launch_bounds__(256) void attn_kernel(
        const unsigned short* __restrict__ qkv,
        unsigned short* __restrict__ aout) {
    __shared__ __align__(16) unsigned short sK[32 * 64];    // [kv][dh]
    __shared__ __align__(16) unsigned short sVt[64 * 32];   // [dh][kv]
    __shared__ __align__(16) unsigned short sP[4][16 * 32]; // per-wave P tile
    const int t = threadIdx.x, w = t >> 6, lane = t & 63;
    const int quad = lane >> 4, l16 = lane & 15;
    const int qtile = blockIdx.x, bh = blockIdx.y;
    const int b = bh >> 4, h = bh & 15;

    // Q fragments (A-layout): A[m=l16][k=quad*8+j]
    const unsigned short* qptr =
        qkv + (size_t)(b * SEQ + qtile * 64 + w * 16 + l16) * QKVN + h * DHEAD;
    const bf16x8 aq0 = *(const bf16x8*)(qptr + quad * 8);
    const bf16x8 aq1 = *(const bf16x8*)(qptr + 32 + quad * 8);

    floatx4 oacc[4];
    float mi[4], li[4];
    #pragma unroll
    for (int i = 0; i < 4; i++) { oacc[i] = (floatx4)0.f; mi[i] = -1e30f; li[i] = 0.f; }

    const unsigned short* kvb = qkv + (size_t)b * SEQ * QKVN;
    const int srow = t >> 3, sc8 = (t & 7) * 8;

    for (int k0 = 0; k0 < SEQ; k0 += 32) {
        // stage K tile [32,64] and V tile transposed [64,32]
        const size_t rbase = (size_t)(k0 + srow) * QKVN + h * DHEAD + sc8;
        *(uint4*)&sK[srow * 64 + sc8] = *(const uint4*)&kvb[rbase + INNER];
        uint4 vv = *(const uint4*)&kvb[rbase + 2 * INNER];
        const unsigned short* vs = (const unsigned short*)&vv;
        #pragma unroll
        for (int j = 0; j < 8; j++) sVt[(sc8 + j) * 32 + srow] = vs[j];
        __syncthreads();

        // S[16 q, 32 kv] = Q Kt (contraction over dh=64 -> 2 MFMA per 16-col strip)
        floatx4 s0 = (floatx4)0.f, s1 = (floatx4)0.f;
        {
            bf16x8 bk;
            bk = *(const bf16x8*)&sK[l16 * 64 + quad * 8];
            s0 = __builtin_amdgcn_mfma_f32_16x16x32_bf16(aq0, bk, s0, 0, 0, 0);
            bk = *(const bf16x8*)&sK[l16 * 64 + 32 + quad * 8];
            s0 = __builtin_amdgcn_mfma_f32_16x16x32_bf16(aq1, bk, s0, 0, 0, 0);
            bk = *(const bf16x8*)&sK[(16 + l16) * 64 + quad * 8];
            s1 = __builtin_amdgcn_mfma_f32_16x16x32_bf16(aq0, bk, s1, 0, 0, 0);
            bk = *(const bf16x8*)&sK[(16 + l16) * 64 + 32 + quad * 8];
            s1 = __builtin_amdgcn_mfma_f32_16x16x32_bf16(aq1, bk, s1, 0, 0, 0);
        }
        // online softmax; C-layout: row q = quad*4+i, col kv = l16 / 16+l16
        float alpha[4];
        #pragma unroll
        for (int i = 0; i < 4; i++) {
            float a0 = s0[i] * ATT_SCALE, a1 = s1[i] * ATT_SCALE;
            float tm = fmaxf(a0, a1);
            for (int off = 8; off >= 1; off >>= 1) tm = fmaxf(tm, __shfl_xor(tm, off));
            float nm = fmaxf(mi[i], tm);
            alpha[i] = __expf(mi[i] - nm);
            mi[i] = nm;
            float p0 = __expf(a0 - nm), p1 = __expf(a1 - nm);
            float rs = p0 + p1;
            for (int off = 8; off >= 1; off >>= 1) rs += __shfl_xor(rs, off);
            li[i] = li[i] * alpha[i] + rs;
            sP[w][(quad * 4 + i) * 32 + l16]      = f2bf(p0);
            sP[w][(quad * 4 + i) * 32 + 16 + l16] = f2bf(p1);
        }
        #pragma unroll
        for (int vt = 0; vt < 4; vt++)
            #pragma unroll
            for (int i = 0; i < 4; i++) oacc[vt][i] *= alpha[i];
        __syncthreads();   // sP C-layout -> A-layout round trip (wave-local, but sync for sVt too)

        // O += P V  (P: A-layout from sP; V: B-layout from sVt, 16B reads)
        const bf16x8 ap = *(const bf16x8*)&sP[w][l16 * 32 + quad * 8];
        #pragma unroll
        for (int vt = 0; vt < 4; vt++) {
            bf16x8 bv = *(const bf16x8*)&sVt[(vt * 16 + l16) * 32 + quad * 8];
            oacc[vt] = __builtin_amdgcn_mfma_f32_16x16x32_bf16(ap, bv, oacc[vt], 0, 0, 0);
        }
        __syncthreads();   // protect sK/sVt before next staging
    }
    #pragma unroll
    for (int vt = 0; vt < 4; vt++)
        #pragma unroll
        for (int i = 0; i < 4; i++) {
            const int row = b * SEQ + qtile * 64 + w * 16 + quad * 4 + i;
            const int col = h * DHEAD + vt * 16 + l16;
            aout[(size_t)row * INNER + col] = f2bf(oacc[vt][i] / li[i]);
        }
}

extern "C" void kernel_launch(void* const* d_in, const int* in_sizes, int n_in,
                              void* d_out, int out_size, void* d_ws, size_t ws_size,
                              hipStream_t stream) {
    const float* x     = (const float*)d_in[0];
    const float* gamma = (const float*)d_in[1];
    const float* beta  = (const float*)d_in[2];
    const float* wqkv  = (const float*)d_in[3];
    const float* wout  = (const float*)d_in[4];
    const float* bout  = (const float*)d_in[5];
    float* out = (float*)d_out;

    unsigned short* ws     = (unsigned short*)d_ws;
    unsigned short* xn     = ws;                                  // 4096x1024 bf16
    unsigned short* wqkvT  = xn     + (size_t)ROWS * DMODEL;      // 3072x1024 bf16
    unsigned short* qkv    = wqkvT  + (size_t)QKVN * DMODEL;      // 4096x3072 bf16
    unsigned short* attnO  = qkv    + (size_t)ROWS * QKVN;        // 4096x1024 bf16
    unsigned short* woutT  = attnO  + (size_t)ROWS * INNER;       // 1024x1024 bf16

    transpose_f2b<<<dim3(QKVN / 32, DMODEL / 32), 256, 0, stream>>>(wqkv, wqkvT, DMODEL, QKVN);
    transpose_f2b<<<dim3(DMODEL / 32, INNER / 32), 256, 0, stream>>>(wout, woutT, INNER, DMODEL);
    ln_kernel<<<ROWS, 256, 0, stream>>>(x, gamma, beta, xn);
    gemm_bt<unsigned short><<<dim3(QKVN / 128, ROWS / 128), 256, 0, stream>>>(
        xn, wqkvT, qkv, ROWS, QKVN, DMODEL, (const float*)nullptr);
    attn_kernel<<<dim3(SEQ / 64, NBATCH * NH), 256, 0, stream>>>(qkv, attnO);
    gemm_bt<float><<<dim3(DMODEL / 128, ROWS / 128), 256, 0, stream>>>(
        attnO, woutT, out, ROWS, DMODEL, INNER, bout);
}

// Round 3
// 237.545 us; speedup vs baseline: 1.6611x; 1.6611x over previous
//
#include <hip/hip_runtime.h>
#include <hip/hip_bf16.h>
#include <stdint.h>

// Problem constants: b=2, s=2048, d=1024, H=16, DH=64, inner=1024
// External tensors FP32; internal bf16 MFMA.
#define NH     16
#define DHEAD  64
#define SEQ    2048
#define DMODEL 1024
#define NBATCH 2
#define INNER  1024
#define QKVN   3072
#define ROWS   4096      // NBATCH*SEQ
#define ATT_SCALE 0.125f // DHEAD^-0.5
#define ATT_QB 128       // q rows per block (32 per wave)
#define ATT_KB 64        // kv rows per iteration

typedef __attribute__((ext_vector_type(8))) __bf16 bf16x8;
typedef __attribute__((ext_vector_type(4))) float floatx4;

__device__ __forceinline__ float bf2f(unsigned short u) {
    union { unsigned int i; float f; } c; c.i = ((unsigned int)u) << 16; return c.f;
}
__device__ __forceinline__ unsigned short f2bf(float f) {
    union { __bf16 b; unsigned short u; } c; c.b = (__bf16)f; return c.u;
}
__device__ __forceinline__ void storeC(float* p, float v) { *p = v; }
__device__ __forceinline__ void storeC(unsigned short* p, float v) { *p = f2bf(v); }

typedef __attribute__((address_space(1))) void gvoid;
typedef __attribute__((address_space(3))) void lvoid;
__device__ __forceinline__ void gl_lds16(const void* g, void* l) {
    __builtin_amdgcn_global_load_lds((gvoid*)g, (lvoid*)l, 16, 0, 0);
}

// ------- transpose + fp32->bf16: out[c][r] = bf16(in[r][c]) ---------------------
__global__ __launch_bounds__(256) void transpose_f2b(
        const float* __restrict__ in, unsigned short* __restrict__ out,
        int rows, int cols) {
    __shared__ unsigned short tile[32][33];
    const int bx = blockIdx.x * 32, by = blockIdx.y * 32;
    const int tx = threadIdx.x & 31, ty = threadIdx.x >> 5;
    for (int i = ty; i < 32; i += 8)
        tile[i][tx] = f2bf(in[(size_t)(by + i) * cols + bx + tx]);
    __syncthreads();
    for (int i = ty; i < 32; i += 8)
        out[(size_t)(bx + i) * rows + by + tx] = tile[tx][i];
}

// ------- per-head V transpose: vT[bh][dh][kv] = qkv[b, kv, 2048 + h*64 + dh] ----
__global__ __launch_bounds__(256) void transpose_v(
        const unsigned short* __restrict__ qkv, unsigned short* __restrict__ vT) {
    __shared__ unsigned short tile[32][33];
    const int bh = blockIdx.y, b = bh >> 4, h = bh & 15;
    const int kv0 = blockIdx.x * 32, dh0 = blockIdx.z * 32;
    const int tx = threadIdx.x & 31, ty = threadIdx.x >> 5;
    for (int i = ty; i < 32; i += 8)
        tile[i][tx] = qkv[(size_t)(b * SEQ + kv0 + i) * QKVN + 2 * INNER + h * DHEAD + dh0 + tx];
    __syncthreads();
    for (int i = ty; i < 32; i += 8)
        vT[((size_t)bh * DHEAD + dh0 + i) * SEQ + kv0 + tx] = tile[tx][i];
}

// ------- layernorm fp32 in -> bf16 out ------------------------------------------
__global__ __launch_bounds__(256) void ln_kernel(
        const float* __restrict__ x,
        const float* __restrict__ gamma,
        const float* __restrict__ beta,
        unsigned short* __restrict__ xn) {
    __shared__ float red[4][2];
    const int row = blockIdx.x, t = threadIdx.x;
    const size_t base = (size_t)row * DMODEL + t * 4;
    float4 v = *(const float4*)(x + base);
    float s  = v.x + v.y + v.z + v.w;
    float ss = v.x*v.x + v.y*v.y + v.z*v.z + v.w*v.w;
    for (int off = 32; off >= 1; off >>= 1) {
        s  += __shfl_xor(s,  off);
        ss += __shfl_xor(ss, off);
    }
    const int w = t >> 6, lane = t & 63;
    if (lane == 0) { red[w][0] = s; red[w][1] = ss; }
    __syncthreads();
    if (t == 0) {
        float S  = red[0][0] + red[1][0] + red[2][0] + red[3][0];
        float SS = red[0][1] + red[1][1] + red[2][1] + red[3][1];
        float mu  = S * (1.f / DMODEL);
        float var = SS * (1.f / DMODEL) - mu * mu;
        red[0][0] = mu; red[0][1] = rsqrtf(var + 1e-5f);
    }
    __syncthreads();
    const float mu = red[0][0], rstd = red[0][1];
    float4 g = *(const float4*)(gamma + t * 4);
    float4 bb = *(const float4*)(beta + t * 4);
    ushort4 o;
    o.x = f2bf((v.x - mu) * rstd * g.x + bb.x);
    o.y = f2bf((v.y - mu) * rstd * g.y + bb.y);
    o.z = f2bf((v.z - mu) * rstd * g.z + bb.z);
    o.w = f2bf((v.w - mu) * rstd * g.w + bb.w);
    *(ushort4*)(xn + base) = o;
}

// ------- C[M,N] = A[M,K] * Bt[N,K]^T (+fp32 bias), 128x128 tile, BK=32 ---------
template <typename OUT>
__global__ __launch_bounds__(256) void gemm_bt(
        const unsigned short* __restrict__ A,
        const unsigned short* __restrict__ Bt,
        OUT* __restrict__ C,
        const int M, const int N, const int K,
        const float* __restrict__ bias) {
    __shared__ __align__(16) unsigned short sA[128 * 32];
    __shared__ __align__(16) unsigned short sB[128 * 32];
    const int t = threadIdx.x;
    const int mBase = blockIdx.y * 128, nBase = blockIdx.x * 128;
    const int w = t >> 6, lane = t & 63, quad = lane >> 4, l16 = lane & 15;
    const int wm = (w >> 1) * 64, wn = (w & 1) * 64;
    floatx4 acc[4][4];
    for (int mi = 0; mi < 4; mi++)
        for (int ni = 0; ni < 4; ni++) acc[mi][ni] = (floatx4)0.f;

    for (int k0 = 0; k0 < K; k0 += 32) {
        #pragma unroll
        for (int c = 0; c < 2; c++) {
            const int idx = c * 256 + t;
            const int row = idx >> 2, colE = (idx & 3) * 8;
            *(uint4*)&sA[row * 32 + colE] =
                *(const uint4*)&A[(size_t)(mBase + row) * K + k0 + colE];
            *(uint4*)&sB[row * 32 + colE] =
                *(const uint4*)&Bt[(size_t)(nBase + row) * K + k0 + colE];
        }
        __syncthreads();
        bf16x8 af[4], bfv[4];
        #pragma unroll
        for (int mi = 0; mi < 4; mi++)
            af[mi] = *(const bf16x8*)&sA[(wm + mi * 16 + l16) * 32 + quad * 8];
        #pragma unroll
        for (int ni = 0; ni < 4; ni++)
            bfv[ni] = *(const bf16x8*)&sB[(wn + ni * 16 + l16) * 32 + quad * 8];
        #pragma unroll
        for (int mi = 0; mi < 4; mi++)
            #pragma unroll
            for (int ni = 0; ni < 4; ni++)
                acc[mi][ni] = __builtin_amdgcn_mfma_f32_16x16x32_bf16(
                    af[mi], bfv[ni], acc[mi][ni], 0, 0, 0);
        __syncthreads();
    }
    #pragma unroll
    for (int mi = 0; mi < 4; mi++)
        #pragma unroll
        for (int ni = 0; ni < 4; ni++) {
            const int col = nBase + wn + ni * 16 + l16;
            const float badd = bias ? bias[col] : 0.f;
            #pragma unroll
            for (int i = 0; i < 4; i++) {
                const int row = mBase + wm + mi * 16 + quad * 4 + i;
                storeC(&C[(size_t)row * N + col], acc[mi][ni][i] + badd);
            }
        }
}

// ------- flash attention, S^T formulation ---------------------------------------
// S^T = K·Q^T  (q = lane column -> per-lane softmax state, 2 shuffles/reduction)
// O^T = V^T·P^T (alpha/l rescale per-lane, no broadcasts)
// K and V^T staged by global_load_lds(16B) into XOR-swizzled LDS (conflict-free
// b128 fragment reads), double-buffered, 1 barrier per 64-wide KV step.
__global__ __launch_bounds__(256) void attn_kernel(
        const unsigned short* __restrict__ qkv,
        const unsigned short* __restrict__ vT,
        unsigned short* __restrict__ aout) {
    __shared__ __align__(16) unsigned short sK[2][ATT_KB * 64];   // [kv][dh-blk swz]
    __shared__ __align__(16) unsigned short sV[2][ATT_KB * 64];   // [dh][kv-blk swz]
    __shared__ __align__(16) unsigned short sP[4][2][16 * 64];    // per wave/strip
    const int t = threadIdx.x, w = t >> 6, lane = t & 63;
    const int quad = lane >> 4, l16 = lane & 15;
    const int bh = blockIdx.y, b = bh >> 4, h = bh & 15;
    const int qbase = blockIdx.x * ATT_QB + w * 32;
    const int swr = l16 & 7;

    // Q fragments (B-operand: B[n=q=l16][k=dh=quad*8+j]), 2 strips x 2 k-halves
    bf16x8 aq[2][2];
    #pragma unroll
    for (int st = 0; st < 2; st++)
        #pragma unroll
        for (int hh = 0; hh < 2; hh++)
            aq[st][hh] = *(const bf16x8*)&qkv[
                (size_t)(b * SEQ + qbase + st * 16 + l16) * QKVN + h * DHEAD + hh * 32 + quad * 8];

    floatx4 oac[2][4];
    float mS[2] = {-1e30f, -1e30f}, lS[2] = {0.f, 0.f};
    #pragma unroll
    for (int st = 0; st < 2; st++)
        #pragma unroll
        for (int c = 0; c < 4; c++) oac[st][c] = (floatx4)0.f;

    const unsigned short* kbase = qkv + (size_t)b * SEQ * QKVN + INNER + h * DHEAD;
    const unsigned short* vbase = vT + (size_t)bh * DHEAD * SEQ;
    const int r8 = lane >> 3, sw8 = ((lane & 7) ^ r8) * 8;

    auto stage = [&](int it, int bi) {
        const int kv0 = it * ATT_KB;
        #pragma unroll
        for (int ii = 0; ii < 2; ii++) {
            const int row = w * 16 + ii * 8 + r8;      // local row 0..63 (row&7==r8)
            gl_lds16(kbase + (size_t)(kv0 + row) * QKVN + sw8,
                     (void*)&sK[bi][(w * 16 + ii * 8) * 64]);
            gl_lds16(vbase + (size_t)row * SEQ + kv0 + sw8,
                     (void*)&sV[bi][(w * 16 + ii * 8) * 64]);
        }
    };
    stage(0, 0);

    for (int it = 0; it < SEQ / ATT_KB; ++it) {
        __syncthreads();                        // drains staging of tile `it`
        if (it + 1 < SEQ / ATT_KB) stage(it + 1, (it + 1) & 1);
        const unsigned short* sKb = &sK[it & 1][0];
        const unsigned short* sVb = &sV[it & 1][0];

        // K fragments (A-operand: A[m=kv=c*16+l16][k=dh=hh*32+quad*8+j])
        bf16x8 kf[4][2];
        #pragma unroll
        for (int c = 0; c < 4; c++)
            #pragma unroll
            for (int hh = 0; hh < 2; hh++)
                kf[c][hh] = *(const bf16x8*)&sKb[(c * 16 + l16) * 64 +
                                                 8 * (((hh << 2) | quad) ^ swr)];
        // S^T: 16 MFMA per strip-pair
        floatx4 sv[2][4];
        #pragma unroll
        for (int st = 0; st < 2; st++)
            #pragma unroll
            for (int c = 0; c < 4; c++) {
                floatx4 acc = (floatx4)0.f;
                acc = __builtin_amdgcn_mfma_f32_16x16x32_bf16(kf[c][0], aq[st][0], acc, 0, 0, 0);
                acc = __builtin_amdgcn_mfma_f32_16x16x32_bf16(kf[c][1], aq[st][1], acc, 0, 0, 0);
                sv[st][c] = acc;
            }
        // softmax (per-lane column q=l16) + pack P into per-strip LDS
        #pragma unroll
        for (int st = 0; st < 2; st++) {
            float a[4][4], mx = -1e30f;
            #pragma unroll
            for (int c = 0; c < 4; c++)
                #pragma unroll
                for (int i = 0; i < 4; i++) {
                    a[c][i] = sv[st][c][i] * ATT_SCALE;
                    mx = fmaxf(mx, a[c][i]);
                }
            mx = fmaxf(mx, __shfl_xor(mx, 16));
            mx = fmaxf(mx, __shfl_xor(mx, 32));
            const float nm = fmaxf(mS[st], mx);
            const float al = __expf(mS[st] - nm);
            mS[st] = nm;
            float sum = 0.f;
            unsigned short* pb = (unsigned short*)&sP[w][st][0];
            #pragma unroll
            for (int c = 0; c < 4; c++) {
                float p0 = __expf(a[c][0] - nm), p1 = __expf(a[c][1] - nm);
                float p2 = __expf(a[c][2] - nm), p3 = __expf(a[c][3] - nm);
                sum += (p0 + p1) + (p2 + p3);
                ushort4 pk;
                pk.x = f2bf(p0); pk.y = f2bf(p1); pk.z = f2bf(p2); pk.w = f2bf(p3);
                *(ushort4*)&pb[l16 * 64 + 8 * ((((c << 1) | (quad >> 1))) ^ swr) + (quad & 1) * 4] = pk;
            }
            sum += __shfl_xor(sum, 16);
            sum += __shfl_xor(sum, 32);
            lS[st] = lS[st] * al + sum;
            #pragma unroll
            for (int c = 0; c < 4; c++) oac[st][c] *= al;
        }
        // V^T fragments (A-operand: A[m=dh=c*16+l16][k=kv=hh*32+quad*8+j])
        bf16x8 vf[4][2];
        #pragma unroll
        for (int c = 0; c < 4; c++)
            #pragma unroll
            for (int hh = 0; hh < 2; hh++)
                vf[c][hh] = *(const bf16x8*)&sVb[(c * 16 + l16) * 64 +
                                                 8 * (((hh << 2) | quad) ^ swr)];
        asm volatile("s_waitcnt lgkmcnt(0)" ::: "memory");  // P stores visible (wave-local)
        #pragma unroll
        for (int st = 0; st < 2; st++) {
            const unsigned short* pb = (const unsigned short*)&sP[w][st][0];
            bf16x8 pf[2];
            #pragma unroll
            for (int hh = 0; hh < 2; hh++)
                pf[hh] = *(const bf16x8*)&pb[l16 * 64 + 8 * (((hh << 2) | quad) ^ swr)];
            #pragma unroll
            for (int c = 0; c < 4; c++) {
                oac[st][c] = __builtin_amdgcn_mfma_f32_16x16x32_bf16(vf[c][0], pf[0], oac[st][c], 0, 0, 0);
                oac[st][c] = __builtin_amdgcn_mfma_f32_16x16x32_bf16(vf[c][1], pf[1], oac[st][c], 0, 0, 0);
            }
        }
    }
    // epilogue: O^T[dh=c*16+quad*4+i][q=l16] -> aout[row=q][col=h*64+dh]
    #pragma unroll
    for (int st = 0; st < 2; st++) {
        const float rl = 1.f / lS[st];
        const size_t rowb = (size_t)(b * SEQ + qbase + st * 16 + l16) * INNER + h * DHEAD;
        #pragma unroll
        for (int c = 0; c < 4; c++) {
            ushort4 o;
            o.x = f2bf(oac[st][c][0] * rl);
            o.y = f2bf(oac[st][c][1] * rl);
            o.z = f2bf(oac[st][c][2] * rl);
            o.w = f2bf(oac[st][c][3] * rl);
            *(ushort4*)&aout[rowb + c * 16 + quad * 4] = o;
        }
    }
}

extern "C" void kernel_launch(void* const* d_in, const int* in_sizes, int n_in,
                              void* d_out, int out_size, void* d_ws, size_t ws_size,
                              hipStream_t stream) {
    const float* x     = (const float*)d_in[0];
    const float* gamma = (const float*)d_in[1];
    const float* beta  = (const float*)d_in[2];
    const float* wqkv  = (const float*)d_in[3];
    const float* wout  = (const float*)d_in[4];
    const float* bout  = (const float*)d_in[5];
    float* out = (float*)d_out;

    unsigned short* ws     = (unsigned short*)d_ws;
    unsigned short* xn     = ws;                                  // 4096x1024 bf16
    unsigned short* wqkvT  = xn     + (size_t)ROWS * DMODEL;      // 3072x1024
    unsigned short* qkv    = wqkvT  + (size_t)QKVN * DMODEL;      // 4096x3072
    unsigned short* attnO  = qkv    + (size_t)ROWS * QKVN;        // 4096x1024
    unsigned short* woutT  = attnO  + (size_t)ROWS * INNER;       // 1024x1024
    unsigned short* vTb    = woutT  + (size_t)DMODEL * INNER;     // 32x64x2048

    transpose_f2b<<<dim3(QKVN / 32, DMODEL / 32), 256, 0, stream>>>(wqkv, wqkvT, DMODEL, QKVN);
    transpose_f2b<<<dim3(DMODEL / 32, INNER / 32), 256, 0, stream>>>(wout, woutT, INNER, DMODEL);
    ln_kernel<<<ROWS, 256, 0, stream>>>(x, gamma, beta, xn);
    gemm_bt<unsigned short><<<dim3(QKVN / 128, ROWS / 128), 256, 0, stream>>>(
        xn, wqkvT, qkv, ROWS, QKVN, DMODEL, (const float*)nullptr);
    transpose_v<<<dim3(SEQ / 32, NBATCH * NH, DHEAD / 32), 256, 0, stream>>>(qkv, vTb);
    attn_kernel<<<dim3(SEQ / ATT_QB, NBATCH * NH), 256, 0, stream>>>(qkv, vTb, attnO);
    gemm_bt<float><<<dim3(DMODEL / 128, ROWS / 128), 256, 0, stream>>>(
        attnO, woutT, out, ROWS, DMODEL, INNER, bout);
}

// Round 4
// 233.031 us; speedup vs baseline: 1.6933x; 1.0194x over previous
//
#include <hip/hip_runtime.h>
#include <hip/hip_bf16.h>
#include <stdint.h>

// Problem constants: b=2, s=2048, d=1024, H=16, DH=64, inner=1024
// External tensors FP32; internal bf16 MFMA.
#define NH     16
#define DHEAD  64
#define SEQ    2048
#define DMODEL 1024
#define NBATCH 2
#define INNER  1024
#define QKVN   3072
#define ROWS   4096      // NBATCH*SEQ
#define ATT_SCALE 0.125f // DHEAD^-0.5
#define ATT_QB 64        // q rows per block (16 per wave)
#define ATT_KB 64        // kv rows per iteration

typedef __attribute__((ext_vector_type(8))) __bf16 bf16x8;
typedef __attribute__((ext_vector_type(4))) float floatx4;

__device__ __forceinline__ float bf2f(unsigned short u) {
    union { unsigned int i; float f; } c; c.i = ((unsigned int)u) << 16; return c.f;
}
__device__ __forceinline__ unsigned short f2bf(float f) {
    union { __bf16 b; unsigned short u; } c; c.b = (__bf16)f; return c.u;
}
__device__ __forceinline__ unsigned int pk2(float a, float b) {
    return (unsigned int)f2bf(a) | ((unsigned int)f2bf(b) << 16);
}
__device__ __forceinline__ void storeC(float* p, float v) { *p = v; }
__device__ __forceinline__ void storeC(unsigned short* p, float v) { *p = f2bf(v); }

typedef __attribute__((address_space(1))) void gvoid;
typedef __attribute__((address_space(3))) void lvoid;
__device__ __forceinline__ void gl_lds16(const void* g, void* l) {
    __builtin_amdgcn_global_load_lds((gvoid*)g, (lvoid*)l, 16, 0, 0);
}

// ------- transpose + fp32->bf16: out[c][r] = bf16(in[r][c]) ---------------------
__global__ __launch_bounds__(256) void transpose_f2b(
        const float* __restrict__ in, unsigned short* __restrict__ out,
        int rows, int cols) {
    __shared__ unsigned short tile[32][33];
    const int bx = blockIdx.x * 32, by = blockIdx.y * 32;
    const int tx = threadIdx.x & 31, ty = threadIdx.x >> 5;
    for (int i = ty; i < 32; i += 8)
        tile[i][tx] = f2bf(in[(size_t)(by + i) * cols + bx + tx]);
    __syncthreads();
    for (int i = ty; i < 32; i += 8)
        out[(size_t)(bx + i) * rows + by + tx] = tile[tx][i];
}

// ------- layernorm fp32 in -> bf16 out ------------------------------------------
__global__ __launch_bounds__(256) void ln_kernel(
        const float* __restrict__ x,
        const float* __restrict__ gamma,
        const float* __restrict__ beta,
        unsigned short* __restrict__ xn) {
    __shared__ float red[4][2];
    const int row = blockIdx.x, t = threadIdx.x;
    const size_t base = (size_t)row * DMODEL + t * 4;
    float4 v = *(const float4*)(x + base);
    float s  = v.x + v.y + v.z + v.w;
    float ss = v.x*v.x + v.y*v.y + v.z*v.z + v.w*v.w;
    for (int off = 32; off >= 1; off >>= 1) {
        s  += __shfl_xor(s,  off);
        ss += __shfl_xor(ss, off);
    }
    const int w = t >> 6, lane = t & 63;
    if (lane == 0) { red[w][0] = s; red[w][1] = ss; }
    __syncthreads();
    if (t == 0) {
        float S  = red[0][0] + red[1][0] + red[2][0] + red[3][0];
        float SS = red[0][1] + red[1][1] + red[2][1] + red[3][1];
        float mu  = S * (1.f / DMODEL);
        float var = SS * (1.f / DMODEL) - mu * mu;
        red[0][0] = mu; red[0][1] = rsqrtf(var + 1e-5f);
    }
    __syncthreads();
    const float mu = red[0][0], rstd = red[0][1];
    float4 g = *(const float4*)(gamma + t * 4);
    float4 bb = *(const float4*)(beta + t * 4);
    ushort4 o;
    o.x = f2bf((v.x - mu) * rstd * g.x + bb.x);
    o.y = f2bf((v.y - mu) * rstd * g.y + bb.y);
    o.z = f2bf((v.z - mu) * rstd * g.z + bb.z);
    o.w = f2bf((v.w - mu) * rstd * g.w + bb.w);
    *(ushort4*)(xn + base) = o;
}

// ------- QKV GEMM: qkv = xn * wqkvT^T, packed epilogue --------------------------
// Writes qP/kP [bh][s][64] and vT [bh][64][s] directly (no qkv buffer).
// 128x128 tile, BK=32, global_load_lds(16B) staging, XOR-swizzled LDS.
__global__ __launch_bounds__(256) void gemm_qkv(
        const unsigned short* __restrict__ A,    // xn [4096,1024]
        const unsigned short* __restrict__ Bt,   // wqkvT [3072,1024]
        unsigned short* __restrict__ qP,
        unsigned short* __restrict__ kP,
        unsigned short* __restrict__ vT) {
    const int K = DMODEL;
    __shared__ __align__(16) unsigned short sA[128 * 32];
    __shared__ __align__(16) unsigned short sB[128 * 32];
    const int t = threadIdx.x;
    const int mBase = blockIdx.y * 128, nBase = blockIdx.x * 128;
    const int w = t >> 6, lane = t & 63, quad = lane >> 4, l16 = lane & 15;
    const int wm = (w >> 1) * 64, wn = (w & 1) * 64;
    const int srow = t >> 2, sch = t & 3;           // staging row/chunk (per 256 idx)
    floatx4 acc[4][4];
    for (int mi = 0; mi < 4; mi++)
        for (int ni = 0; ni < 4; ni++) acc[mi][ni] = (floatx4)0.f;

    for (int k0 = 0; k0 < K; k0 += 32) {
        #pragma unroll
        for (int c = 0; c < 2; c++) {
            const int row = c * 64 + srow;
            const int gcol = (sch ^ ((row >> 1) & 3)) * 8;
            gl_lds16(&A[(size_t)(mBase + row) * K + k0 + gcol], &sA[(c * 256 + w * 64) * 8]);
            gl_lds16(&Bt[(size_t)(nBase + row) * K + k0 + gcol], &sB[(c * 256 + w * 64) * 8]);
        }
        __syncthreads();
        bf16x8 af[4], bfv[4];
        #pragma unroll
        for (int mi = 0; mi < 4; mi++) {
            const int r = wm + mi * 16 + l16;
            af[mi] = *(const bf16x8*)&sA[r * 32 + (quad ^ ((r >> 1) & 3)) * 8];
        }
        #pragma unroll
        for (int ni = 0; ni < 4; ni++) {
            const int r = wn + ni * 16 + l16;
            bfv[ni] = *(const bf16x8*)&sB[r * 32 + (quad ^ ((r >> 1) & 3)) * 8];
        }
        #pragma unroll
        for (int mi = 0; mi < 4; mi++)
            #pragma unroll
            for (int ni = 0; ni < 4; ni++)
                acc[mi][ni] = __builtin_amdgcn_mfma_f32_16x16x32_bf16(
                    af[mi], bfv[ni], acc[mi][ni], 0, 0, 0);
        __syncthreads();
    }
    // packed epilogue
    #pragma unroll
    for (int ni = 0; ni < 4; ni++) {
        const int col = nBase + wn + ni * 16 + l16;   // 0..3071
        const int reg = col >> 10;                    // 0=q 1=k 2=v (uniform)
        const int h   = (col & 1023) >> 6;
        const int dh  = col & 63;
        #pragma unroll
        for (int mi = 0; mi < 4; mi++) {
            const int row0 = mBase + wm + mi * 16 + quad * 4;
            const int b = row0 >> 11, s0 = row0 & 2047;
            const int bh = b * NH + h;
            if (reg == 2) {
                ushort4 o;
                o.x = f2bf(acc[mi][ni][0]); o.y = f2bf(acc[mi][ni][1]);
                o.z = f2bf(acc[mi][ni][2]); o.w = f2bf(acc[mi][ni][3]);
                *(ushort4*)&vT[((size_t)bh * DHEAD + dh) * SEQ + s0] = o;
            } else {
                unsigned short* dst = (reg == 0 ? qP : kP);
                #pragma unroll
                for (int i = 0; i < 4; i++)
                    dst[((size_t)bh * SEQ + s0 + i) * DHEAD + dh] = f2bf(acc[mi][ni][i]);
            }
        }
    }
}

// ------- out GEMM: C[M,N] = A[M,K]*Bt[N,K]^T + bias (fp32 out) ------------------
__global__ __launch_bounds__(256) void gemm_out(
        const unsigned short* __restrict__ A,
        const unsigned short* __restrict__ Bt,
        float* __restrict__ C,
        const int M, const int N, const int K,
        const float* __restrict__ bias) {
    __shared__ __align__(16) unsigned short sA[128 * 32];
    __shared__ __align__(16) unsigned short sB[128 * 32];
    const int t = threadIdx.x;
    const int mBase = blockIdx.y * 128, nBase = blockIdx.x * 128;
    const int w = t >> 6, lane = t & 63, quad = lane >> 4, l16 = lane & 15;
    const int wm = (w >> 1) * 64, wn = (w & 1) * 64;
    const int srow = t >> 2, sch = t & 3;
    floatx4 acc[4][4];
    for (int mi = 0; mi < 4; mi++)
        for (int ni = 0; ni < 4; ni++) acc[mi][ni] = (floatx4)0.f;

    for (int k0 = 0; k0 < K; k0 += 32) {
        #pragma unroll
        for (int c = 0; c < 2; c++) {
            const int row = c * 64 + srow;
            const int gcol = (sch ^ ((row >> 1) & 3)) * 8;
            gl_lds16(&A[(size_t)(mBase + row) * K + k0 + gcol], &sA[(c * 256 + w * 64) * 8]);
            gl_lds16(&Bt[(size_t)(nBase + row) * K + k0 + gcol], &sB[(c * 256 + w * 64) * 8]);
        }
        __syncthreads();
        bf16x8 af[4], bfv[4];
        #pragma unroll
        for (int mi = 0; mi < 4; mi++) {
            const int r = wm + mi * 16 + l16;
            af[mi] = *(const bf16x8*)&sA[r * 32 + (quad ^ ((r >> 1) & 3)) * 8];
        }
        #pragma unroll
        for (int ni = 0; ni < 4; ni++) {
            const int r = wn + ni * 16 + l16;
            bfv[ni] = *(const bf16x8*)&sB[r * 32 + (quad ^ ((r >> 1) & 3)) * 8];
        }
        #pragma unroll
        for (int mi = 0; mi < 4; mi++)
            #pragma unroll
            for (int ni = 0; ni < 4; ni++)
                acc[mi][ni] = __builtin_amdgcn_mfma_f32_16x16x32_bf16(
                    af[mi], bfv[ni], acc[mi][ni], 0, 0, 0);
        __syncthreads();
    }
    #pragma unroll
    for (int mi = 0; mi < 4; mi++)
        #pragma unroll
        for (int ni = 0; ni < 4; ni++) {
            const int col = nBase + wn + ni * 16 + l16;
            const float badd = bias ? bias[col] : 0.f;
            #pragma unroll
            for (int i = 0; i < 4; i++) {
                const int row = mBase + wm + mi * 16 + quad * 4 + i;
                C[(size_t)row * N + col] = acc[mi][ni][i] + badd;
            }
        }
}

// ------- flash attention, S^T formulation, bpermute P-relayout ------------------
// 4 waves x 16 q rows, KV tile 64 double-buffered, 1 barrier/iter, no sP LDS.
__global__ __launch_bounds__(256, 4) void attn_kernel(
        const unsigned short* __restrict__ qP,
        const unsigned short* __restrict__ kP,
        const unsigned short* __restrict__ vT,
        unsigned short* __restrict__ aout) {
    __shared__ __align__(16) unsigned short sK[2][ATT_KB * 64];   // [kv][dh swz]
    __shared__ __align__(16) unsigned short sV[2][ATT_KB * 64];   // [dh][kv swz]
    const int t = threadIdx.x, w = t >> 6, lane = t & 63;
    const int quad = lane >> 4, l16 = lane & 15;
    const int bh = blockIdx.y;
    const int qrow = blockIdx.x * ATT_QB + w * 16 + l16;          // within seq
    const int swr = l16 & 7;

    // Q fragments (B-operand: B[n=q=l16][k=dh=quad*8+j])
    const unsigned short* qb = qP + ((size_t)bh * SEQ + qrow) * DHEAD;
    bf16x8 aq[2];
    aq[0] = *(const bf16x8*)(qb + quad * 8);
    aq[1] = *(const bf16x8*)(qb + 32 + quad * 8);

    floatx4 oac[4];
    float mS = -1e30f, lS = 0.f;
    #pragma unroll
    for (int c = 0; c < 4; c++) oac[c] = (floatx4)0.f;

    const unsigned short* kb = kP + (size_t)bh * SEQ * DHEAD;
    const unsigned short* vb = vT + (size_t)bh * DHEAD * SEQ;
    const int r8 = lane >> 3, sw8 = ((lane & 7) ^ r8) * 8;

    auto stage = [&](int it, int bi) {
        const int kv0 = it * ATT_KB;
        #pragma unroll
        for (int ii = 0; ii < 2; ii++) {
            const int row = w * 16 + ii * 8 + r8;   // local row (row&7==r8)
            gl_lds16(kb + (size_t)(kv0 + row) * DHEAD + sw8,
                     (void*)&sK[bi][(w * 16 + ii * 8) * 64]);
            gl_lds16(vb + (size_t)row * SEQ + kv0 + sw8,
                     (void*)&sV[bi][(w * 16 + ii * 8) * 64]);
        }
    };
    stage(0, 0);

    const int adrA = ((quad & 1) * 32 + l16) * 4;   // src lane byte addr (s0)
    const int adrB = adrA + 64;                     // s0+16 lanes

    for (int it = 0; it < SEQ / ATT_KB; ++it) {
        __syncthreads();                  // staging of tile `it` complete
        if (it + 1 < SEQ / ATT_KB) stage(it + 1, (it + 1) & 1);
        const unsigned short* sKb = &sK[it & 1][0];
        const unsigned short* sVb = &sV[it & 1][0];

        // K frags (A-operand: A[m=kv=c*16+l16][k=dh=hh*32+quad*8+j])
        bf16x8 kf[4][2];
        #pragma unroll
        for (int c = 0; c < 4; c++)
            #pragma unroll
            for (int hh = 0; hh < 2; hh++)
                kf[c][hh] = *(const bf16x8*)&sKb[(c * 16 + l16) * 64 +
                                                 8 * (((hh << 2) | quad) ^ swr)];
        // S^T tiles: sv[c] covers kv=c*16+quad*4+i at q=l16
        floatx4 sv[4];
        #pragma unroll
        for (int c = 0; c < 4; c++) {
            floatx4 a = (floatx4)0.f;
            a = __builtin_amdgcn_mfma_f32_16x16x32_bf16(kf[c][0], aq[0], a, 0, 0, 0);
            a = __builtin_amdgcn_mfma_f32_16x16x32_bf16(kf[c][1], aq[1], a, 0, 0, 0);
            sv[c] = a;
        }
        // online softmax, per-lane column q=l16 (state replicated over quads)
        float mx = -1e30f;
        #pragma unroll
        for (int c = 0; c < 4; c++)
            #pragma unroll
            for (int i = 0; i < 4; i++) {
                sv[c][i] *= ATT_SCALE;
                mx = fmaxf(mx, sv[c][i]);
            }
        mx = fmaxf(mx, __shfl_xor(mx, 16));
        mx = fmaxf(mx, __shfl_xor(mx, 32));
        const float nm = fmaxf(mS, mx);
        const float al = __expf(mS - nm);
        mS = nm;
        float sum = 0.f;
        uint2 pkc[4];
        #pragma unroll
        for (int c = 0; c < 4; c++) {
            float p0 = __expf(sv[c][0] - nm), p1 = __expf(sv[c][1] - nm);
            float p2 = __expf(sv[c][2] - nm), p3 = __expf(sv[c][3] - nm);
            sum += (p0 + p1) + (p2 + p3);
            pkc[c].x = pk2(p0, p1);
            pkc[c].y = pk2(p2, p3);
        }
        sum += __shfl_xor(sum, 16);
        sum += __shfl_xor(sum, 32);
        lS = lS * al + sum;
        #pragma unroll
        for (int c = 0; c < 4; c++) oac[c] *= al;

        // P relayout: C-layout -> B-operand via ds_bpermute (wave-local)
        const bool sel = (quad < 2);
        bf16x8 pf[2];
        #pragma unroll
        for (int hh = 0; hh < 2; hh++) {
            const uint2 cl = pkc[2 * hh], ch = pkc[2 * hh + 1];
            int a0 = __builtin_amdgcn_ds_bpermute(adrA, (int)cl.x);
            int b0 = __builtin_amdgcn_ds_bpermute(adrA, (int)ch.x);
            int a1 = __builtin_amdgcn_ds_bpermute(adrA, (int)cl.y);
            int b1 = __builtin_amdgcn_ds_bpermute(adrA, (int)ch.y);
            int a2 = __builtin_amdgcn_ds_bpermute(adrB, (int)cl.x);
            int b2 = __builtin_amdgcn_ds_bpermute(adrB, (int)ch.x);
            int a3 = __builtin_amdgcn_ds_bpermute(adrB, (int)cl.y);
            int b3 = __builtin_amdgcn_ds_bpermute(adrB, (int)ch.y);
            union { int i[4]; bf16x8 v; } u;
            u.i[0] = sel ? a0 : b0;
            u.i[1] = sel ? a1 : b1;
            u.i[2] = sel ? a2 : b2;
            u.i[3] = sel ? a3 : b3;
            pf[hh] = u.v;
        }
        // V^T frags (A-operand: A[m=dh=c*16+l16][k=kv=hh*32+quad*8+j])
        #pragma unroll
        for (int c = 0; c < 4; c++) {
            bf16x8 v0 = *(const bf16x8*)&sVb[(c * 16 + l16) * 64 + 8 * ((quad) ^ swr)];
            bf16x8 v1 = *(const bf16x8*)&sVb[(c * 16 + l16) * 64 + 8 * ((4 | quad) ^ swr)];
            oac[c] = __builtin_amdgcn_mfma_f32_16x16x32_bf16(v0, pf[0], oac[c], 0, 0, 0);
            oac[c] = __builtin_amdgcn_mfma_f32_16x16x32_bf16(v1, pf[1], oac[c], 0, 0, 0);
        }
    }
    // epilogue: O^T[dh=c*16+quad*4+i][q=l16] ; lane's own q row = qrow
    const float rl = 1.f / lS;
    const int b = bh >> 4, h = bh & 15;
    const size_t rowb = ((size_t)(b * SEQ + qrow)) * INNER + h * DHEAD;
    #pragma unroll
    for (int c = 0; c < 4; c++) {
        ushort4 o;
        o.x = f2bf(oac[c][0] * rl);
        o.y = f2bf(oac[c][1] * rl);
        o.z = f2bf(oac[c][2] * rl);
        o.w = f2bf(oac[c][3] * rl);
        *(ushort4*)&aout[rowb + c * 16 + quad * 4] = o;
    }
}

extern "C" void kernel_launch(void* const* d_in, const int* in_sizes, int n_in,
                              void* d_out, int out_size, void* d_ws, size_t ws_size,
                              hipStream_t stream) {
    const float* x     = (const float*)d_in[0];
    const float* gamma = (const float*)d_in[1];
    const float* beta  = (const float*)d_in[2];
    const float* wqkv  = (const float*)d_in[3];
    const float* wout  = (const float*)d_in[4];
    const float* bout  = (const float*)d_in[5];
    float* out = (float*)d_out;

    unsigned short* ws     = (unsigned short*)d_ws;
    unsigned short* xn     = ws;                                  // 4096x1024
    unsigned short* wqkvT  = xn     + (size_t)ROWS * DMODEL;      // 3072x1024
    unsigned short* qPb    = wqkvT  + (size_t)QKVN * DMODEL;      // 32x2048x64
    unsigned short* kPb    = qPb    + (size_t)NBATCH * NH * SEQ * DHEAD;
    unsigned short* vTb    = kPb    + (size_t)NBATCH * NH * SEQ * DHEAD;
    unsigned short* attnO  = vTb    + (size_t)NBATCH * NH * SEQ * DHEAD; // 4096x1024
    unsigned short* woutT  = attnO  + (size_t)ROWS * INNER;       // 1024x1024

    transpose_f2b<<<dim3(QKVN / 32, DMODEL / 32), 256, 0, stream>>>(wqkv, wqkvT, DMODEL, QKVN);
    transpose_f2b<<<dim3(DMODEL / 32, INNER / 32), 256, 0, stream>>>(wout, woutT, INNER, DMODEL);
    ln_kernel<<<ROWS, 256, 0, stream>>>(x, gamma, beta, xn);
    gemm_qkv<<<dim3(QKVN / 128, ROWS / 128), 256, 0, stream>>>(xn, wqkvT, qPb, kPb, vTb);
    attn_kernel<<<dim3(SEQ / ATT_QB, NBATCH * NH), 256, 0, stream>>>(qPb, kPb, vTb, attnO);
    gemm_out<<<dim3(DMODEL / 128, ROWS / 128), 256, 0, stream>>>(
        attnO, woutT, out, ROWS, DMODEL, INNER, bout);
}